// Round 8
// baseline (56.497 us; speedup 1.0000x reference)
//
#include <hip/hip_runtime.h>
#include <hip/hip_bf16.h>

#define B_ 8
#define G_ 1024
#define HD_ 1024
#define EPS_ 1e-5f
#define AGENT_ __HIP_MEMORY_SCOPE_AGENT

// NOTE: The reference's BatchNorm over the G axis (training mode, batch stats)
// makes the output invariant to any per-(b,j) constant added to H @ fc_w.T.
// The broadcast-qemb half of H and fc_b are such constants -> the whole GIN
// pipeline cannot affect d_out. Only gPos, allDBGEmb, fc_w[:,1024:], bn3, fc2
// matter. (Verified R3 vs R4: identical absmax.)
// R5 lesson: cooperative launch + grid.sync costs ~45 us -> use co-resident
// blocks + device-scope atomic handshake instead (grid=256 <= 1 block/CU,
// LDS 38KB -> >=4 blocks/CU capacity, so all blocks always resident).
// R7 lesson: keep stage/compute overlap (double-buffer); single-stage gather
// serializes HBM latency ahead of MFMA and loses ~4 us.

typedef __attribute__((ext_vector_type(8))) short bf16x8;
typedef __attribute__((ext_vector_type(4))) float f32x4;

__device__ inline short bf1(float x) {
    return (short)__builtin_bit_cast(unsigned short, __float2bfloat16(x));
}
__device__ inline bf16x8 cvt8(float4 a, float4 b) {
    bf16x8 o;
    o[0] = bf1(a.x); o[1] = bf1(a.y); o[2] = bf1(a.z); o[3] = bf1(a.w);
    o[4] = bf1(b.x); o[5] = bf1(b.y); o[6] = bf1(b.z); o[7] = bf1(b.w);
    return o;
}

// ---------- fc_w[:,1024:2048] -> bf16 in MFMA B-fragment order; zero sync ----------
// frag f = kt*8 + jblk (kt = k/32, jblk = j/16); lane l holds
// B[k = kt*32 + (l>>4)*8 + i][j = jblk*16 + (l&15)], i = 0..7.
__global__ __launch_bounds__(256) void k_w2cvt(const float* __restrict__ fc_w,
                                               short* __restrict__ w2arr,
                                               int* __restrict__ sync_) {
    int gid = blockIdx.x * 256 + threadIdx.x;  // 0 .. 32*8*64-1
    if (blockIdx.x == 0 && threadIdx.x < 16) sync_[threadIdx.x] = 0;
    int kt = gid >> 9;
    int jblk = (gid >> 6) & 7;
    int lane = gid & 63;
    int j = jblk * 16 + (lane & 15);
    int k = kt * 32 + (lane >> 4) * 8;
    const float4* sp = (const float4*)&fc_w[(size_t)j * (2 * HD_) + HD_ + k];
    *(bf16x8*)&w2arr[(size_t)gid * 8] = cvt8(sp[0], sp[1]);
}

#define SLABW 258  // 32 rows * 8 shorts + 2 pad per 8-k slab

// ---------- fused GEMM + BN3 + relu + fc2 + sigmoid ----------
// grid (32, 8), 512 thr = 8 waves. BK=256, 4 double-buffered phases.
// Wave (gq,jq): 16g x 32j via 16x16x32 MFMA; B direct from w2arr (L2).
// After GEMM: publish BN partials (agent atomics), last block per graph
// reduces -> scale/shift, flag; all blocks finish from in-register acc.
__global__ __launch_bounds__(512) void k_gemm(const int* __restrict__ gPos,
                                              const float* __restrict__ emb,
                                              const short* __restrict__ w2arr,
                                              const float* __restrict__ g3,
                                              const float* __restrict__ b3,
                                              const float* __restrict__ fc2w,
                                              const float* __restrict__ fc2b,
                                              float* __restrict__ ps,
                                              float* __restrict__ pq,
                                              float* __restrict__ scv,
                                              float* __restrict__ shv,
                                              int* __restrict__ sync_,
                                              float* __restrict__ out) {
    int b = blockIdx.y, gblk = blockIdx.x;
    int gbase = gblk * 32;
    int tid = threadIdx.x;
    int wave = tid >> 6, lane = tid & 63;
    int gq = wave >> 2, jq = wave & 3;
    int l15 = lane & 15, kb = lane >> 4;

    __shared__ short As[2][32 * SLABW];  // 33 KB
    __shared__ float sp4[4][128], sq4[4][128];
    __shared__ float wred[4][32];
    __shared__ int lastflag;

    int arow = tid >> 4, acp = tid & 15;
    const float* abase = emb + (size_t)gPos[b * G_ + gbase + arow] * HD_;

    {   // prologue: stage phase 0 (k chunks acp, acp+16)
        const float4* a0 = (const float4*)(abase + acp * 8);
        const float4* a1 = (const float4*)(abase + (acp + 16) * 8);
        *(bf16x8*)&As[0][acp * SLABW + arow * 8] = cvt8(a0[0], a0[1]);
        *(bf16x8*)&As[0][(acp + 16) * SLABW + arow * 8] = cvt8(a1[0], a1[1]);
    }
    __syncthreads();

    f32x4 acc0 = {0.f, 0.f, 0.f, 0.f}, acc1 = {0.f, 0.f, 0.f, 0.f};
    for (int p = 0; p < 4; ++p) {
        int cur = p & 1;
        if (p < 3) {
            const float* ab = abase + (p + 1) * 256;
            const float4* a0 = (const float4*)(ab + acp * 8);
            const float4* a1 = (const float4*)(ab + (acp + 16) * 8);
            *(bf16x8*)&As[cur ^ 1][acp * SLABW + arow * 8] = cvt8(a0[0], a0[1]);
            *(bf16x8*)&As[cur ^ 1][(acp + 16) * SLABW + arow * 8] = cvt8(a1[0], a1[1]);
        }
#pragma unroll
        for (int kt = 0; kt < 8; ++kt) {
            int f = (p * 8 + kt) * 8 + jq * 2;
            bf16x8 b0 = *(const bf16x8*)&w2arr[((size_t)f * 64 + lane) * 8];
            bf16x8 b1 = *(const bf16x8*)&w2arr[((size_t)(f + 1) * 64 + lane) * 8];
            bf16x8 a = *(const bf16x8*)&As[cur][(kt * 4 + kb) * SLABW + (gq * 16 + l15) * 8];
            acc0 = __builtin_amdgcn_mfma_f32_16x16x32_bf16(a, b0, acc0, 0, 0, 0);
            acc1 = __builtin_amdgcn_mfma_f32_16x16x32_bf16(a, b1, acc1, 0, 0, 0);
        }
        __syncthreads();
    }

    // ---- publish BN partials (per (b, gblk, gq) slot; no z buffer) ----
    int col0 = jq * 32 + l15, col1 = col0 + 16;
    {
        float s0 = 0.f, q0 = 0.f, s1 = 0.f, q1 = 0.f;
#pragma unroll
        for (int r = 0; r < 4; ++r) {  // C/D: col=lane&15, row=(lane>>4)*4+r
            float v0 = acc0[r], v1 = acc1[r];
            s0 += v0; q0 += v0 * v0;
            s1 += v1; q1 += v1 * v1;
        }
        s0 += __shfl_xor(s0, 16, 64); s0 += __shfl_xor(s0, 32, 64);
        q0 += __shfl_xor(q0, 16, 64); q0 += __shfl_xor(q0, 32, 64);
        s1 += __shfl_xor(s1, 16, 64); s1 += __shfl_xor(s1, 32, 64);
        q1 += __shfl_xor(q1, 16, 64); q1 += __shfl_xor(q1, 32, 64);
        if (lane < 16) {
            int slot = (b * 64 + gblk * 2 + gq) * 128;
            __hip_atomic_store(&ps[slot + col0], s0, __ATOMIC_RELAXED, AGENT_);
            __hip_atomic_store(&pq[slot + col0], q0, __ATOMIC_RELAXED, AGENT_);
            __hip_atomic_store(&ps[slot + col1], s1, __ATOMIC_RELAXED, AGENT_);
            __hip_atomic_store(&pq[slot + col1], q1, __ATOMIC_RELAXED, AGENT_);
        }
    }
    __syncthreads();
    if (tid == 0) {
        int old = __hip_atomic_fetch_add(&sync_[b], 1, __ATOMIC_ACQ_REL, AGENT_);
        lastflag = (old == 31);
    }
    __syncthreads();

    if (lastflag) {  // last block of graph b: reduce 64 slots -> scale/shift
        int sgrp = tid >> 7, j = tid & 127;
        float ss = 0.f, qq = 0.f;
        for (int t = sgrp; t < 64; t += 4) {
            ss += __hip_atomic_load(&ps[(b * 64 + t) * 128 + j], __ATOMIC_RELAXED, AGENT_);
            qq += __hip_atomic_load(&pq[(b * 64 + t) * 128 + j], __ATOMIC_RELAXED, AGENT_);
        }
        sp4[sgrp][j] = ss;
        sq4[sgrp][j] = qq;
        __syncthreads();
        if (tid < 128) {
            float S = sp4[0][tid] + sp4[1][tid] + sp4[2][tid] + sp4[3][tid];
            float Q = sq4[0][tid] + sq4[1][tid] + sq4[2][tid] + sq4[3][tid];
            float mu = S * (1.f / G_);
            float var = Q * (1.f / G_) - mu * mu;
            float sc = g3[tid] * rsqrtf(var + EPS_);
            __hip_atomic_store(&scv[b * 128 + tid], sc, __ATOMIC_RELAXED, AGENT_);
            __hip_atomic_store(&shv[b * 128 + tid], b3[tid] - mu * sc,
                               __ATOMIC_RELAXED, AGENT_);
        }
        __syncthreads();
        if (tid == 0)
            __hip_atomic_store(&sync_[8 + b], 1, __ATOMIC_RELEASE, AGENT_);
    }

    if (tid == 0) {
        while (__hip_atomic_load(&sync_[8 + b], __ATOMIC_ACQUIRE, AGENT_) == 0) {}
    }
    __syncthreads();

    // ---- finish: BN + relu + fc2 dot + sigmoid from in-register acc ----
    float sc0 = __hip_atomic_load(&scv[b * 128 + col0], __ATOMIC_RELAXED, AGENT_);
    float sc1 = __hip_atomic_load(&scv[b * 128 + col1], __ATOMIC_RELAXED, AGENT_);
    float sh0 = __hip_atomic_load(&shv[b * 128 + col0], __ATOMIC_RELAXED, AGENT_);
    float sh1 = __hip_atomic_load(&shv[b * 128 + col1], __ATOMIC_RELAXED, AGENT_);
    float w0 = fc2w[col0], w1 = fc2w[col1];
#pragma unroll
    for (int r = 0; r < 4; ++r) {
        float t = fmaxf(fmaf(acc0[r], sc0, sh0), 0.f) * w0 +
                  fmaxf(fmaf(acc1[r], sc1, sh1), 0.f) * w1;
        t += __shfl_xor(t, 1, 64);
        t += __shfl_xor(t, 2, 64);
        t += __shfl_xor(t, 4, 64);
        t += __shfl_xor(t, 8, 64);
        if (l15 == 0) wred[jq][gq * 16 + kb * 4 + r] = t;
    }
    __syncthreads();
    if (tid < 32) {
        float tot = wred[0][tid] + wred[1][tid] + wred[2][tid] + wred[3][tid] + fc2b[0];
        out[b * G_ + gbase + tid] = 1.f / (1.f + expf(-tot));
    }
}

extern "C" void kernel_launch(void* const* d_in, const int* in_sizes, int n_in,
                              void* d_out, int out_size, void* d_ws, size_t ws_size,
                              hipStream_t stream) {
    const int*   gPos = (const int*)d_in[3];
    const float* emb  = (const float*)d_in[4];
    const float* fc_w = (const float*)d_in[11];
    const float* bn3g = (const float*)d_in[13];
    const float* bn3b = (const float*)d_in[14];
    const float* fc2w = (const float*)d_in[15];
    const float* fc2b = (const float*)d_in[16];
    float* out = (float*)d_out;

    char* w = (char*)d_ws;
    short* w2arr = (short*)w; w += (size_t)128 * HD_ * 2;       // 256 KB
    float* ps    = (float*)w; w += (size_t)B_ * 64 * 128 * 4;   // 256 KB
    float* pq    = (float*)w; w += (size_t)B_ * 64 * 128 * 4;   // 256 KB
    float* scv   = (float*)w; w += (size_t)B_ * 128 * 4;
    float* shv   = (float*)w; w += (size_t)B_ * 128 * 4;
    int*   sync_ = (int*)w;   w += 64;

    k_w2cvt<<<64, 256, 0, stream>>>(fc_w, w2arr, sync_);
    k_gemm<<<dim3(32, B_), 512, 0, stream>>>(gPos, emb, w2arr, bn3g, bn3b,
                                             fc2w, fc2b, ps, pq, scv, shv, sync_, out);
}

// Round 9
// 34.201 us; speedup vs baseline: 1.6519x; 1.6519x over previous
//
#include <hip/hip_runtime.h>
#include <hip/hip_bf16.h>

#define B_ 8
#define G_ 1024
#define HD_ 1024
#define EPS_ 1e-5f

// NOTE: The reference's BatchNorm over the G axis (training mode, batch stats)
// makes the output invariant to any per-(b,j) constant added to H @ fc_w.T.
// The broadcast-qemb half of H and fc_b are such constants -> the whole GIN
// pipeline cannot affect d_out. Only gPos, allDBGEmb, fc_w[:,1024:], bn3, fc2
// matter. (Verified R3 vs R4: identical absmax.)
// R5/R8 lesson: ANY grid-wide sync (cooperative or atomic handshake) costs
// 27-45 us here -> kernel boundaries are the cheapest dependency.
// R7 lesson: keep stage/compute overlap (double-buffer); single-stage gather
// serializes HBM latency ahead of MFMA (-4 us).

typedef __attribute__((ext_vector_type(8))) short bf16x8;
typedef __attribute__((ext_vector_type(4))) float f32x4;

__device__ inline short bf1(float x) {
    return (short)__builtin_bit_cast(unsigned short, __float2bfloat16(x));
}
__device__ inline bf16x8 cvt8(float4 a, float4 b) {
    bf16x8 o;
    o[0] = bf1(a.x); o[1] = bf1(a.y); o[2] = bf1(a.z); o[3] = bf1(a.w);
    o[4] = bf1(b.x); o[5] = bf1(b.y); o[6] = bf1(b.z); o[7] = bf1(b.w);
    return o;
}
__device__ inline float bf2f(unsigned short u) {
    return __builtin_bit_cast(float, (unsigned)u << 16);
}

// ---------- fc_w[:,1024:2048] -> bf16 in MFMA B-fragment order ----------
// frag f = kt*8 + jblk (kt = k/32, jblk = j/16); lane l holds
// B[k = kt*32 + (l>>4)*8 + i][j = jblk*16 + (l&15)], i = 0..7.
__global__ __launch_bounds__(256) void k_w2cvt(const float* __restrict__ fc_w,
                                               short* __restrict__ w2arr) {
    int gid = blockIdx.x * 256 + threadIdx.x;  // 0 .. 32*8*64-1
    int kt = gid >> 9;
    int jblk = (gid >> 6) & 7;
    int lane = gid & 63;
    int j = jblk * 16 + (lane & 15);
    int k = kt * 32 + (lane >> 4) * 8;
    const float4* sp = (const float4*)&fc_w[(size_t)j * (2 * HD_) + HD_ + k];
    *(bf16x8*)&w2arr[(size_t)gid * 8] = cvt8(sp[0], sp[1]);
}

#define ASLAB 258  // 32 rows * 8 shorts + 2 pad per 8-k slab

// ---------- z[b][g][j] = emb[gPos[b][g]] . fc_w[j][1024:2048] ----------
// grid (32, 8), 512 thr = 8 waves; wave (gq,jq) does 16g x 32j via 16x16x32.
// A: LDS double-buffered (gathered emb rows, f32->bf16). B: direct from w2arr
// (register fragments, L2-resident, no LDS).  [= R6 proven body; z now bf16]
__global__ __launch_bounds__(512) void k_gemm(const int* __restrict__ gPos,
                                              const float* __restrict__ emb,
                                              const short* __restrict__ w2arr,
                                              short* __restrict__ zb,
                                              float* __restrict__ ps,
                                              float* __restrict__ pq) {
    int b = blockIdx.y, gblk = blockIdx.x;
    int gbase = gblk * 32;
    int tid = threadIdx.x;
    int wave = tid >> 6, lane = tid & 63;
    int gq = wave >> 2, jq = wave & 3;
    int l15 = lane & 15, kb = lane >> 4;  // kb = 0..3

    __shared__ int gidx[32];
    __shared__ short As[2][16 * ASLAB];

    if (tid < 32) gidx[tid] = gPos[b * G_ + gbase + tid];
    __syncthreads();

    int arow = tid >> 4, acp = tid & 15;  // 512 thr: one bf16x8 slab piece each
    const float* abase = emb + (size_t)gidx[arow] * HD_;

    f32x4 acc0 = {0.f, 0.f, 0.f, 0.f}, acc1 = {0.f, 0.f, 0.f, 0.f};

    {   // prologue: stage phase 0
        const float4* ap = (const float4*)(abase + acp * 8);
        *(bf16x8*)&As[0][acp * ASLAB + arow * 8] = cvt8(ap[0], ap[1]);
    }
    __syncthreads();

    for (int p = 0; p < 8; ++p) {
        int cur = p & 1;
        if (p < 7) {
            const float4* ap = (const float4*)(abase + (p + 1) * 128 + acp * 8);
            *(bf16x8*)&As[cur ^ 1][acp * ASLAB + arow * 8] = cvt8(ap[0], ap[1]);
        }
#pragma unroll
        for (int kt = 0; kt < 4; ++kt) {
            bf16x8 a = *(const bf16x8*)&As[cur][(kt * 4 + kb) * ASLAB + (gq * 16 + l15) * 8];
            int f = (p * 4 + kt) * 8 + jq * 2;
            bf16x8 b0 = *(const bf16x8*)&w2arr[((size_t)f * 64 + lane) * 8];
            bf16x8 b1 = *(const bf16x8*)&w2arr[((size_t)(f + 1) * 64 + lane) * 8];
            acc0 = __builtin_amdgcn_mfma_f32_16x16x32_bf16(a, b0, acc0, 0, 0, 0);
            acc1 = __builtin_amdgcn_mfma_f32_16x16x32_bf16(a, b1, acc1, 0, 0, 0);
        }
        __syncthreads();
    }

    // epilogue: bf16 z write + per-(gblk,gq) BN partials from exact f32 acc
    int col0 = jq * 32 + l15, col1 = col0 + 16;
    float s0 = 0.f, q0 = 0.f, s1 = 0.f, q1 = 0.f;
#pragma unroll
    for (int r = 0; r < 4; ++r) {
        int g = gbase + gq * 16 + kb * 4 + r;  // C/D: col=lane&15, row=(lane>>4)*4+reg
        float z0 = acc0[r], z1 = acc1[r];
        zb[(size_t)(b * G_ + g) * 128 + col0] = bf1(z0);
        zb[(size_t)(b * G_ + g) * 128 + col1] = bf1(z1);
        s0 += z0; q0 += z0 * z0;
        s1 += z1; q1 += z1 * z1;
    }
    s0 += __shfl_xor(s0, 16, 64); s0 += __shfl_xor(s0, 32, 64);
    q0 += __shfl_xor(q0, 16, 64); q0 += __shfl_xor(q0, 32, 64);
    s1 += __shfl_xor(s1, 16, 64); s1 += __shfl_xor(s1, 32, 64);
    q1 += __shfl_xor(q1, 16, 64); q1 += __shfl_xor(q1, 32, 64);
    if (lane < 16) {
        int slot = (b * 64 + gblk * 2 + gq) * 128;
        ps[slot + col0] = s0; pq[slot + col0] = q0;
        ps[slot + col1] = s1; pq[slot + col1] = q1;
    }
}

// ---------- fused BN3 stats + apply + relu + fc2 + sigmoid ----------
// grid (16, 8), 256 thr; block reduces its graph's 64 partial slots
// (redundant x16, L2-resident) then processes 64 g rows.
__global__ __launch_bounds__(256) void k_final(const short* __restrict__ zb,
                                               const float* __restrict__ ps,
                                               const float* __restrict__ pq,
                                               const float* __restrict__ g3,
                                               const float* __restrict__ b3,
                                               const float* __restrict__ fc2w,
                                               const float* __restrict__ fc2b,
                                               float* __restrict__ out) {
    int b = blockIdx.y, gseg = blockIdx.x;
    int tid = threadIdx.x, wave = tid >> 6, lane = tid & 63;
    __shared__ float scL[128], shL[128];
    if (tid < 128) {
        int j = tid;
        float s = 0.f, q = 0.f;
#pragma unroll 8
        for (int t = 0; t < 64; ++t) {
            s += ps[(b * 64 + t) * 128 + j];
            q += pq[(b * 64 + t) * 128 + j];
        }
        float mu = s * (1.f / G_);
        float var = q * (1.f / G_) - mu * mu;
        float sc = g3[j] * rsqrtf(var + EPS_);
        scL[j] = sc;
        shL[j] = b3[j] - mu * sc;
    }
    __syncthreads();
    int j0 = lane * 2;
    float sc0 = scL[j0], sc1 = scL[j0 + 1];
    float sh0 = shL[j0], sh1 = shL[j0 + 1];
    float w0 = fc2w[j0], w1 = fc2w[j0 + 1], bias = fc2b[0];
#pragma unroll
    for (int it = 0; it < 16; ++it) {
        int g = gseg * 64 + it * 4 + wave;
        const ushort2* zr = (const ushort2*)(zb + (size_t)(b * G_ + g) * 128);
        ushort2 u = zr[lane];
        float acc = fmaxf(fmaf(bf2f(u.x), sc0, sh0), 0.f) * w0 +
                    fmaxf(fmaf(bf2f(u.y), sc1, sh1), 0.f) * w1;
        acc += __shfl_xor(acc, 32, 64);
        acc += __shfl_xor(acc, 16, 64);
        acc += __shfl_xor(acc, 8, 64);
        acc += __shfl_xor(acc, 4, 64);
        acc += __shfl_xor(acc, 2, 64);
        acc += __shfl_xor(acc, 1, 64);
        if (lane == 0) out[b * G_ + g] = 1.f / (1.f + expf(-(acc + bias)));
    }
}

extern "C" void kernel_launch(void* const* d_in, const int* in_sizes, int n_in,
                              void* d_out, int out_size, void* d_ws, size_t ws_size,
                              hipStream_t stream) {
    const int*   gPos = (const int*)d_in[3];
    const float* emb  = (const float*)d_in[4];
    const float* fc_w = (const float*)d_in[11];
    const float* bn3g = (const float*)d_in[13];
    const float* bn3b = (const float*)d_in[14];
    const float* fc2w = (const float*)d_in[15];
    const float* fc2b = (const float*)d_in[16];
    float* out = (float*)d_out;

    char* w = (char*)d_ws;
    short* zb    = (short*)w; w += (size_t)B_ * G_ * 128 * 2;   // 2 MB
    short* w2arr = (short*)w; w += (size_t)128 * HD_ * 2;       // 256 KB
    float* ps    = (float*)w; w += (size_t)B_ * 64 * 128 * 4;   // 256 KB
    float* pq    = (float*)w; w += (size_t)B_ * 64 * 128 * 4;   // 256 KB

    k_w2cvt<<<64, 256, 0, stream>>>(fc_w, w2arr);
    k_gemm<<<dim3(32, B_), 512, 0, stream>>>(gPos, emb, w2arr, zb, ps, pq);
    k_final<<<dim3(16, B_), 256, 0, stream>>>(zb, ps, pq, bn3g, bn3b, fc2w, fc2b, out);
}